// Round 10
// baseline (300.179 us; speedup 1.0000x reference)
//
#include <hip/hip_runtime.h>

#define TT 4
#define NN 50000
#define DH 64
#define EE 800000
#define BN_EPS 1e-5f
#define G1 64           // prep blocks per t
#define EB 2048         // fill blocks (all-resident)
#define AGG_B 2048      // k_agg blocks per pass (8/CU x 4 waves)
#define AGG_W (AGG_B*4) // k_agg waves per pass
#define MAIN_B 768      // k_main blocks (3/CU at ~160 VGPR, all-resident)
#define FOLD_B 8        // k_fold blocks
#define CAP 32          // bucket = exactly one 128B line; P(deg>32)~5e-5, exact backstop
#define DSTR 8          // deg counter stride in ints (32B apart -> 64 atomics/line)
#define PASLOT 32       // PA partial slots (k_fold loop length)
#define OVMAX 256       // overflow-list capacity

typedef __attribute__((ext_vector_type(8))) short short8;
typedef __attribute__((ext_vector_type(4))) float floatx4;

// ---------------- ws layout (byte offsets) ----------------
#define WS_PA       0          // [PASLOT][64] f = 8,192
#define WS_PA2      8192       // -> 16,384
#define WS_PX       16384      // [4][G1][64] f -> 81,920
#define WS_PX2      81920      // -> 147,456
#define WS_W1EFF    147456     // 12288 bf16 -> 172,032
#define WS_B1EFF    172032     // 64 f -> 172,288
#define WS_OVC      172288     // 1 int (pad to 256B)
#define WS_OVF      172544     // OVMAX int4 = 4,096 -> 176,640
#define WS_DEG      176640     // 50000*DSTR ints = 1,600,000 -> 1,776,640 (128B-mult)
#define WS_PACKED   1776640    // 50000*CAP u32 = 6,400,000 -> 8,176,640 (128B buckets)
#define WS_XB       8176640    // 25.6 MB bf16 [N][T][DH] -> 33,776,640
#define WS_AVGB     33776640   // 25.6 MB -> 59,376,640 (< granted 59,678,720)

__device__ __forceinline__ unsigned short f2b(float f) {
    unsigned int u = __float_as_uint(f);
    unsigned int r = (u + 0x7FFFu + ((u >> 16) & 1u)) >> 16;
    return (unsigned short)r;
}
__device__ __forceinline__ float b2f(unsigned short u) {
    return __uint_as_float((unsigned int)u << 16);
}
__device__ __forceinline__ unsigned short f2h(float f) {
    _Float16 h = (_Float16)f;                 // RTE
    unsigned short u; __builtin_memcpy(&u, &h, 2); return u;
}
__device__ __forceinline__ float h2f(unsigned short u) {
    _Float16 h; __builtin_memcpy(&h, &u, 2); return (float)h;
}

// x(fp32, NT-load) -> xb(bf16, [N][T][DH]) + per-(t,c) stats partials; zeroes deg+ovc
__global__ __launch_bounds__(256) void k_prep_stats(
    const float* __restrict__ x, unsigned short* __restrict__ xb,
    float* __restrict__ PX, float* __restrict__ PX2,
    int* __restrict__ deg, int* __restrict__ ovc) {
    int t = blockIdx.y;
    int tid = threadIdx.x;
    int gid = (t * G1 + blockIdx.x) * 256 + tid;       // 0..65535 unique
    int4* deg4 = (int4*)deg;                           // zero 1.6MB strided table
    for (int i = gid; i < NN * DSTR / 4; i += 65536)
        deg4[i] = make_int4(0, 0, 0, 0);
    if (gid == 0) *ovc = 0;

    int g = blockIdx.x * 256 + tid;
    const floatx4* xt = (const floatx4*)(x + (size_t)t * NN * 64);
    float s[4] = {0.f, 0.f, 0.f, 0.f}, s2[4] = {0.f, 0.f, 0.f, 0.f};
    for (int v = g; v < NN * 16; v += G1 * 256) {      // stride mult of 16 -> c-group fixed
        floatx4 d = __builtin_nontemporal_load(&xt[v]); // x never re-read
        ushort4 o;
        o.x = f2b(d.x); o.y = f2b(d.y); o.z = f2b(d.z); o.w = f2b(d.w);
        // interleaved dst: node = v>>4, channel = (v&15)*4
        *(ushort4*)(xb + (size_t)(v >> 4) * 256 + t * 64 + (v & 15) * 4) = o;
        s[0] += d.x; s2[0] += d.x * d.x;
        s[1] += d.y; s2[1] += d.y * d.y;
        s[2] += d.z; s2[2] += d.z * d.z;
        s[3] += d.w; s2[3] += d.w * d.w;
    }
    __shared__ float ls[256 * 4], ls2[256 * 4];
#pragma unroll
    for (int j = 0; j < 4; ++j) { ls[tid * 4 + j] = s[j]; ls2[tid * 4 + j] = s2[j]; }
    __syncthreads();
    if (tid < 64) {
        int g16 = tid >> 2, comp = tid & 3;
        float rs = 0.f, rs2 = 0.f;
#pragma unroll
        for (int k = 0; k < 16; ++k) {
            int j = g16 + 16 * k;
            rs += ls[j * 4 + comp]; rs2 += ls2[j * 4 + comp];
        }
        int slot = (t * G1 + blockIdx.x) * 64 + tid;
        PX[slot] = rs; PX2[slot] = rs2;
    }
}

// single-pass bucket build: slot = atomicAdd(deg[dst*DSTR]); packed[dst*CAP+slot]
// = (src:u16 | f16(w):u16). Counters strided 32B (64 atomics/line). Bucket =
// one 128B line. Overflow (deg>CAP) -> tiny exact list. Zeroes PA/PA2.
__global__ __launch_bounds__(256) void k_fillB(
    const int* __restrict__ src, const int* __restrict__ dst,
    const float* __restrict__ ew, int* __restrict__ deg,
    unsigned int* __restrict__ packed, int* __restrict__ ovc,
    int4* __restrict__ ovf, float* __restrict__ PA) {
    int gtid = blockIdx.x * 256 + threadIdx.x;
    if (gtid < 2 * PASLOT * 64) PA[gtid] = 0.f;        // PA + PA2 (contiguous)
    for (int e = gtid; e < EE; e += EB * 256) {
        int d = dst[e];
        int s = src[e];
        float w = ew[e];
        int slot = atomicAdd(&deg[d * DSTR], 1);
        if (slot < CAP) {
            packed[d * CAP + slot] = (unsigned int)s | ((unsigned int)f2h(w) << 16);
        } else {
            int o = atomicAdd(ovc, 1);
            if (o < OVMAX) ovf[o] = make_int4(d, s, __float_as_int(w), 0);
        }
    }
}

// t-SPLIT aggregation pass: one wave per node, gathers only the 128B t-slice
// per edge -> per-pass working set 6.4MB (vs 25.6) for higher L2 hit rate.
// Lane l: eh = l>>4 (edge slot 0-3), j = l&15 (8B channel chunk). One gather
// instruction covers 4 edges x 128B. 8-edge window = 2 gathers. Cross-edge
// combine via shfl_xor(16/32); lanes 0-15 write the t-slice + fused stats.
__global__ __launch_bounds__(256) void k_aggT(
    const unsigned short* __restrict__ xb, const unsigned int* __restrict__ packed,
    const int* __restrict__ deg, const int* __restrict__ ovc,
    const int4* __restrict__ ovf, unsigned short* __restrict__ avgb,
    float* __restrict__ PA, float* __restrict__ PA2, int t) {
    int wv = __builtin_amdgcn_readfirstlane(threadIdx.x >> 6);
    int tid = threadIdx.x;
    int l = tid & 63;
    int eh = l >> 4;                               // edge slot within group of 4
    int j = l & 15;                                // 8B chunk (4 channels)
    int wgid = blockIdx.x * 4 + wv;
    const ushort4* xq = (const ushort4*)xb + (size_t)t * 16 + j;  // + src*64 per edge
    int nov = *ovc; nov = nov > OVMAX ? OVMAX : nov;
    float sA[4] = {0.f, 0.f, 0.f, 0.f}, sA2[4] = {0.f, 0.f, 0.f, 0.f};

    for (int n = wgid; n < NN; n += AGG_W) {
        int dg = deg[n * DSTR];
        int cnt = dg < CAP ? dg : CAP;
        const unsigned int* bkt = packed + n * CAP;
        float a0 = 0.f, a1 = 0.f, a2 = 0.f, a3 = 0.f, wsum = 0.f;
        for (int e = 0; e < cnt; e += 8) {
            int rem = cnt - e;                     // uniform; >=1
            unsigned int p[8];
#pragma unroll
            for (int q = 0; q < 8; ++q) p[q] = bkt[e + q];     // scalar 32B
            // select this lane's edges (eh, eh+4) from the uniform window
            unsigned int pe0 = (eh == 0) ? p[0] : (eh == 1) ? p[1] : (eh == 2) ? p[2] : p[3];
            unsigned int pe1 = (eh == 0) ? p[4] : (eh == 1) ? p[5] : (eh == 2) ? p[6] : p[7];
            bool ok0 = (eh < rem);
            bool ok1 = (eh + 4 < rem);
            int  s0 = ok0 ? (int)(pe0 & 0xFFFFu) : 0;
            int  s1 = ok1 ? (int)(pe1 & 0xFFFFu) : 0;
            ushort4 v0 = xq[(size_t)s0 * 64];
            ushort4 v1 = xq[(size_t)s1 * 64];
            float w0 = ok0 ? h2f((unsigned short)(pe0 >> 16)) : 0.f;
            float w1 = ok1 ? h2f((unsigned short)(pe1 >> 16)) : 0.f;
            wsum += w0 + w1;
            a0 = fmaf(w0, b2f(v0.x), a0); a0 = fmaf(w1, b2f(v1.x), a0);
            a1 = fmaf(w0, b2f(v0.y), a1); a1 = fmaf(w1, b2f(v1.y), a1);
            a2 = fmaf(w0, b2f(v0.z), a2); a2 = fmaf(w1, b2f(v1.z), a2);
            a3 = fmaf(w0, b2f(v0.w), a3); a3 = fmaf(w1, b2f(v1.w), a3);
        }
        if (dg > CAP) {                            // exact backstop, ~never taken
            for (int o = 0; o < nov; ++o) {
                int4 E = ovf[o];
                if (E.x == n) {
                    float w = (eh == 0) ? __int_as_float(E.z) : 0.f;  // count once
                    ushort4 v = xq[(size_t)E.y * 64];
                    wsum += w;
                    a0 = fmaf(w, b2f(v.x), a0); a1 = fmaf(w, b2f(v.y), a1);
                    a2 = fmaf(w, b2f(v.z), a2); a3 = fmaf(w, b2f(v.w), a3);
                }
            }
        }
        // combine the 4 edge slots: lanes l, l^16, l^32(+48) share (j, channels)
        a0 += __shfl_xor(a0, 16); a0 += __shfl_xor(a0, 32);
        a1 += __shfl_xor(a1, 16); a1 += __shfl_xor(a1, 32);
        a2 += __shfl_xor(a2, 16); a2 += __shfl_xor(a2, 32);
        a3 += __shfl_xor(a3, 16); a3 += __shfl_xor(a3, 32);
        wsum += __shfl_xor(wsum, 16); wsum += __shfl_xor(wsum, 32);

        if (eh == 0) {                             // lanes 0-15 own the result
            float rz = (wsum == 0.f) ? 1.f : (1.f / wsum);
            ushort4 o;
            o.x = f2b(a0 * rz); o.y = f2b(a1 * rz);
            o.z = f2b(a2 * rz); o.w = f2b(a3 * rz);
            *((ushort4*)avgb + (size_t)n * 64 + (size_t)t * 16 + j) = o;  // 128B/node
            float f0 = b2f(o.x), f1 = b2f(o.y), f2v = b2f(o.z), f3 = b2f(o.w);
            sA[0] += f0; sA2[0] += f0 * f0;
            sA[1] += f1; sA2[1] += f1 * f1;
            sA[2] += f2v; sA2[2] += f2v * f2v;
            sA[3] += f3; sA2[3] += f3 * f3;
        }
    }

    __shared__ float ls[256 * 4], ls2[256 * 4];
#pragma unroll
    for (int q = 0; q < 4; ++q) { ls[tid * 4 + q] = sA[q]; ls2[tid * 4 + q] = sA2[q]; }
    __syncthreads();
    if (tid < 64) {
        // channel c = (lane&15)*4 + q (only eh==0 lanes nonzero); slot tid = channel tid
        int g15 = tid >> 2, q = tid & 3;
        float rs = 0.f, rs2 = 0.f;
#pragma unroll
        for (int k = 0; k < 16; ++k) {
            int st = k * 16 + g15;
            rs += ls[st * 4 + q]; rs2 += ls2[st * 4 + q];
        }
        int slot = (blockIdx.x & (PASLOT - 1)) * 64 + tid;   // 64 adds/address/pass
        atomicAdd(&PA[slot], rs);
        atomicAdd(&PA2[slot], rs2);
    }
}

// stage-2 reduce + BN fold into bf16 W1eff / fp32 b1eff.
// Parallel stage-1: 256 threads = (t-part p, channel cc); max serial loop = 64.
__global__ __launch_bounds__(256) void k_fold(
    const float* __restrict__ W1, const float* __restrict__ b1,
    const float* __restrict__ gamma, const float* __restrict__ beta,
    const float* __restrict__ PX, const float* __restrict__ PX2,
    const float* __restrict__ PA, const float* __restrict__ PA2,
    unsigned short* __restrict__ W1eff, float* __restrict__ b1eff) {
    __shared__ float spx[4][64], spx2[4][64], spa[64], spa2[64];
    __shared__ float gS[192], hS[192];
    int tid = threadIdx.x;
    int p = tid >> 6, cc = tid & 63;
    float s = 0.f, s2 = 0.f;
    for (int b = 0; b < G1; ++b) {          // PX slot = (t*G1 + b)*64 + c, p == t
        int i = (p * G1 + b) * 64 + cc;
        s += PX[i]; s2 += PX2[i];
    }
    spx[p][cc] = s; spx2[p][cc] = s2;
    if (tid < 64) {
        float a = 0.f, a2 = 0.f;
        for (int i = 0; i < PASLOT; ++i) { a += PA[i * 64 + tid]; a2 += PA2[i * 64 + tid]; }
        spa[tid] = a; spa2[tid] = a2;
    }
    __syncthreads();
    const float inv = 1.0f / (float)(TT * NN);
    if (tid < 192) {
        int c = tid;
        float ss, ss2;
        if (c < 64) {
            ss  = spx[0][c] + spx[1][c] + spx[2][c] + spx[3][c];
            ss2 = spx2[0][c] + spx2[1][c] + spx2[2][c] + spx2[3][c];
        } else if (c < 128) {
            int k = c - 64;                 // prev: t=0..2 only
            ss  = spx[0][k] + spx[1][k] + spx[2][k];
            ss2 = spx2[0][k] + spx2[1][k] + spx2[2][k];
        } else {
            int k = c - 128;
            ss = spa[k]; ss2 = spa2[k];
        }
        float mu = ss * inv, ex2 = ss2 * inv;
        float var = ex2 - mu * mu;
        float g = gamma[c] / sqrtf(var + BN_EPS);
        gS[c] = g;
        hS[c] = beta[c] - mu * g;
    }
    __syncthreads();
    if (tid < 192) {
        // slice stride FOLD_B*192 keeps (i mod 192) == tid
        for (int i = blockIdx.x * 192 + tid; i < 64 * 192; i += FOLD_B * 192)
            W1eff[i] = f2b(W1[i] * gS[tid]);
    }
    if (tid < 8) {
        int o = blockIdx.x * 8 + tid;       // 8 blocks x 8 = 64 outputs
        float acc = b1[o];
        for (int c = 0; c < 192; ++c) acc += hS[c] * W1[o * 192 + c];
        b1eff[o] = acc;
    }
}

// MFMA GEMM: block = 4 waves, wave = 16 rows x 64 outs, K=192.
// W1eff register-hoisted (identical for every tile): 24 x short8 = 96 VGPR;
// per tile only 6 A-loads + 24 MFMA + stores. (256,3): 3 blocks/CU resident.
__global__ __launch_bounds__(256, 3) void k_main(
    const unsigned short* __restrict__ xb, const unsigned short* __restrict__ avgb,
    const unsigned short* __restrict__ Wb, const float* __restrict__ bias,
    float* __restrict__ out) {
    int wave = threadIdx.x >> 6;
    int lane = threadIdx.x & 63;
    int m = lane & 15;
    int q = lane >> 4;
    const short8 zf = (short8){0, 0, 0, 0, 0, 0, 0, 0};

    short8 bw[6][4];                        // whole folded W, register-resident
#pragma unroll
    for (int kc = 0; kc < 6; ++kc)
#pragma unroll
        for (int ct = 0; ct < 4; ++ct)
            bw[kc][ct] = *(const short8*)(Wb + (size_t)(ct * 16 + m) * 192 + kc * 32 + q * 8);
    float bv[4];
#pragma unroll
    for (int ct = 0; ct < 4; ++ct) bv[ct] = bias[ct * 16 + m];

    for (int tile = blockIdx.x; tile < (TT * NN) / 64; tile += MAIN_B) {
        int r0 = tile * 64 + wave * 16;     // wave-uniform t (16 divides 50000)
        int t = r0 / NN;
        int n0 = r0 - t * NN;
        size_t nb = (size_t)(n0 + m) * 256 + (size_t)t * 64 + q * 8;
        const unsigned short* xrow = xb + nb;
        const unsigned short* arow = avgb + nb;
        bool has_prev = (t >= 1);

        short8 a[6];                        // all 6 A-frags issued up front
        a[0] = *(const short8*)(xrow);
        a[1] = *(const short8*)(xrow + 32);
        a[2] = has_prev ? *(const short8*)(xrow - 64) : zf;
        a[3] = has_prev ? *(const short8*)(xrow - 32) : zf;
        a[4] = *(const short8*)(arow);
        a[5] = *(const short8*)(arow + 32);

        floatx4 acc[4];
#pragma unroll
        for (int ct = 0; ct < 4; ++ct) acc[ct] = (floatx4){0.f, 0.f, 0.f, 0.f};
#pragma unroll
        for (int kc = 0; kc < 6; ++kc)
#pragma unroll
            for (int ct = 0; ct < 4; ++ct)
                acc[ct] = __builtin_amdgcn_mfma_f32_16x16x32_bf16(a[kc], bw[kc][ct], acc[ct], 0, 0, 0);

#pragma unroll
        for (int ct = 0; ct < 4; ++ct)
#pragma unroll
            for (int i = 0; i < 4; ++i) {
                int row = q * 4 + i;
                __builtin_nontemporal_store(fmaxf(acc[ct][i] + bv[ct], 0.f),
                                            &out[(size_t)(r0 + row) * 64 + ct * 16 + m]);
            }
    }
}

extern "C" void kernel_launch(void* const* d_in, const int* in_sizes, int n_in,
                              void* d_out, int out_size, void* d_ws, size_t ws_size,
                              hipStream_t stream) {
    const float* x     = (const float*)d_in[0];
    const float* ew    = (const float*)d_in[1];
    const float* W1    = (const float*)d_in[2];
    const float* b1    = (const float*)d_in[3];
    const float* gamma = (const float*)d_in[4];
    const float* beta  = (const float*)d_in[5];
    const int*   src   = (const int*)d_in[6];
    const int*   dst   = (const int*)d_in[7];
    float* out = (float*)d_out;
    char*  ws  = (char*)d_ws;

    float* PA       = (float*)(ws + WS_PA);
    float* PA2      = (float*)(ws + WS_PA2);
    float* PX       = (float*)(ws + WS_PX);
    float* PX2      = (float*)(ws + WS_PX2);
    unsigned short* W1eff = (unsigned short*)(ws + WS_W1EFF);
    float* b1eff    = (float*)(ws + WS_B1EFF);
    int*   ovc      = (int*)(ws + WS_OVC);
    int4*  ovf      = (int4*)(ws + WS_OVF);
    int*   deg      = (int*)(ws + WS_DEG);
    unsigned int* packed = (unsigned int*)(ws + WS_PACKED);
    unsigned short* xb   = (unsigned short*)(ws + WS_XB);
    unsigned short* avgb = (unsigned short*)(ws + WS_AVGB);

    k_prep_stats<<<dim3(G1, TT), 256, 0, stream>>>(x, xb, PX, PX2, deg, ovc);

    k_fillB<<<EB, 256, 0, stream>>>(src, dst, ew, deg, packed, ovc, ovf, PA);

    k_aggT<<<AGG_B, 256, 0, stream>>>(xb, packed, deg, ovc, ovf, avgb, PA, PA2, 0);
    k_aggT<<<AGG_B, 256, 0, stream>>>(xb, packed, deg, ovc, ovf, avgb, PA, PA2, 1);
    k_aggT<<<AGG_B, 256, 0, stream>>>(xb, packed, deg, ovc, ovf, avgb, PA, PA2, 2);
    k_aggT<<<AGG_B, 256, 0, stream>>>(xb, packed, deg, ovc, ovf, avgb, PA, PA2, 3);

    k_fold<<<FOLD_B, 256, 0, stream>>>(W1, b1, gamma, beta, PX, PX2, PA, PA2, W1eff, b1eff);

    k_main<<<MAIN_B, 256, 0, stream>>>(xb, avgb, W1eff, b1eff, out);
}

// Round 11
// 270.713 us; speedup vs baseline: 1.1088x; 1.1088x over previous
//
#include <hip/hip_runtime.h>

#define TT 4
#define NN 50000
#define DH 64
#define EE 800000
#define BN_EPS 1e-5f
#define G1 64           // prep blocks per t
#define EB 2048         // fill blocks (all-resident)
#define AGG_B 2048      // k_agg blocks per dispatch (8/CU x 4 waves)
#define AGG_W (AGG_B*4) // k_agg waves per dispatch
#define MAIN_B 768      // k_main blocks (3/CU at ~160 VGPR, all-resident)
#define FOLD_B 8        // k_fold blocks
#define CAP 32          // bucket = exactly one 128B line; P(deg>32)~5e-5, exact backstop
#define DSTR 8          // deg counter stride in ints (32B apart)
#define PASLOT 32       // PA partial slots (k_fold loop length)
#define OVMAX 256       // overflow-list capacity
#define EHALF 400000    // fillB edge split
#define NHALF 25000     // agg node split

typedef __attribute__((ext_vector_type(8))) short short8;
typedef __attribute__((ext_vector_type(4))) float floatx4;

// ---------------- ws layout (byte offsets) ----------------
#define WS_PA       0          // [PASLOT][64] f = 8,192
#define WS_PA2      8192       // -> 16,384
#define WS_PX       16384      // [4][G1][64] f -> 81,920
#define WS_PX2      81920      // -> 147,456
#define WS_W1EFF    147456     // 12288 bf16 -> 172,032
#define WS_B1EFF    172032     // 64 f -> 172,288
#define WS_OVC      172288     // 1 int (pad to 256B)
#define WS_OVF      172544     // OVMAX int4 = 4,096 -> 176,640
#define WS_DEG      176640     // 50000*DSTR ints = 1,600,000 -> 1,776,640 (128B-mult)
#define WS_PACKED   1776640    // 50000*CAP u32 = 6,400,000 -> 8,176,640 (128B buckets)
#define WS_XB       8176640    // 25.6 MB bf16 [N][T][DH] -> 33,776,640
#define WS_AVGB     33776640   // 25.6 MB -> 59,376,640 (< granted 59,678,720)

__device__ __forceinline__ unsigned short f2b(float f) {
    unsigned int u = __float_as_uint(f);
    unsigned int r = (u + 0x7FFFu + ((u >> 16) & 1u)) >> 16;
    return (unsigned short)r;
}
__device__ __forceinline__ float b2f(unsigned short u) {
    return __uint_as_float((unsigned int)u << 16);
}
__device__ __forceinline__ unsigned short f2h(float f) {
    _Float16 h = (_Float16)f;                 // RTE
    unsigned short u; __builtin_memcpy(&u, &h, 2); return u;
}
__device__ __forceinline__ float h2f(unsigned short u) {
    _Float16 h; __builtin_memcpy(&h, &u, 2); return (float)h;
}

// x(fp32, NT-load) -> xb(bf16, [N][T][DH]) + per-(t,c) stats partials; zeroes deg+ovc
__global__ __launch_bounds__(256) void k_prep_stats(
    const float* __restrict__ x, unsigned short* __restrict__ xb,
    float* __restrict__ PX, float* __restrict__ PX2,
    int* __restrict__ deg, int* __restrict__ ovc) {
    int t = blockIdx.y;
    int tid = threadIdx.x;
    int gid = (t * G1 + blockIdx.x) * 256 + tid;       // 0..65535 unique
    int4* deg4 = (int4*)deg;                           // zero 1.6MB strided table
    for (int i = gid; i < NN * DSTR / 4; i += 65536)
        deg4[i] = make_int4(0, 0, 0, 0);
    if (gid == 0) *ovc = 0;

    int g = blockIdx.x * 256 + tid;
    const floatx4* xt = (const floatx4*)(x + (size_t)t * NN * 64);
    float s[4] = {0.f, 0.f, 0.f, 0.f}, s2[4] = {0.f, 0.f, 0.f, 0.f};
    for (int v = g; v < NN * 16; v += G1 * 256) {      // stride mult of 16 -> c-group fixed
        floatx4 d = __builtin_nontemporal_load(&xt[v]); // x never re-read
        ushort4 o;
        o.x = f2b(d.x); o.y = f2b(d.y); o.z = f2b(d.z); o.w = f2b(d.w);
        // interleaved dst: node = v>>4, channel = (v&15)*4
        *(ushort4*)(xb + (size_t)(v >> 4) * 256 + t * 64 + (v & 15) * 4) = o;
        s[0] += d.x; s2[0] += d.x * d.x;
        s[1] += d.y; s2[1] += d.y * d.y;
        s[2] += d.z; s2[2] += d.z * d.z;
        s[3] += d.w; s2[3] += d.w * d.w;
    }
    __shared__ float ls[256 * 4], ls2[256 * 4];
#pragma unroll
    for (int j = 0; j < 4; ++j) { ls[tid * 4 + j] = s[j]; ls2[tid * 4 + j] = s2[j]; }
    __syncthreads();
    if (tid < 64) {
        int g16 = tid >> 2, comp = tid & 3;
        float rs = 0.f, rs2 = 0.f;
#pragma unroll
        for (int k = 0; k < 16; ++k) {
            int j = g16 + 16 * k;
            rs += ls[j * 4 + comp]; rs2 += ls2[j * 4 + comp];
        }
        int slot = (t * G1 + blockIdx.x) * 64 + tid;
        PX[slot] = rs; PX2[slot] = rs2;
    }
}

// single-pass bucket build over edge range [lo,hi): slot = atomicAdd(deg[dst*DSTR]);
// packed[dst*CAP+slot] = (src:u16 | f16(w):u16). Bucket = one 128B line.
// Overflow (deg>CAP) -> tiny exact list. At the device-coherent atomic
// throughput wall (~13 G/s; stride/CAP tuning measured null, r5 vs r10).
__global__ __launch_bounds__(256) void k_fillB(
    const int* __restrict__ src, const int* __restrict__ dst,
    const float* __restrict__ ew, int* __restrict__ deg,
    unsigned int* __restrict__ packed, int* __restrict__ ovc,
    int4* __restrict__ ovf, float* __restrict__ PA, int lo, int hi) {
    int gtid = blockIdx.x * 256 + threadIdx.x;
    if (lo == 0 && gtid < 2 * PASLOT * 64) PA[gtid] = 0.f;   // PA + PA2 (contiguous)
    for (int e = lo + gtid; e < hi; e += EB * 256) {
        int d = dst[e];
        int s = src[e];
        float w = ew[e];
        int slot = atomicAdd(&deg[d * DSTR], 1);
        if (slot < CAP) {
            packed[d * CAP + slot] = (unsigned int)s | ((unsigned int)f2h(w) << 16);
        } else {
            int o = atomicAdd(ovc, 1);
            if (o < OVMAX) ovf[o] = make_int4(d, s, __float_as_int(w), 0);
        }
    }
}

// one wave per node over [lo,hi), grid-strided; wave-uniform node -> scalar
// s_load of bucket windows. Interleaved [N][T][DH]: one edge = one contiguous
// 512B gather, lane offset l*8B. Tail masked. deg>CAP nodes scan the exact
// overflow list. Fused avg-stats atomicAdd'ed into PA[blockIdx&31].
// At the random-gather service ceiling (~3.6 TB/s; 4 structures converged).
__global__ __launch_bounds__(256) void k_agg(
    const unsigned short* __restrict__ xb, const unsigned int* __restrict__ packed,
    const int* __restrict__ deg, const int* __restrict__ ovc,
    const int4* __restrict__ ovf, unsigned short* __restrict__ avgb,
    float* __restrict__ PA, float* __restrict__ PA2, int lo, int hi) {
    int wv = __builtin_amdgcn_readfirstlane(threadIdx.x >> 6);
    int tid = threadIdx.x;
    int l = tid & 63;
    int wgid = blockIdx.x * 4 + wv;
    const ushort4* xl = (const ushort4*)xb + l;   // + src*64 per edge
    int nov = *ovc; nov = nov > OVMAX ? OVMAX : nov;
    float sA[4] = {0.f, 0.f, 0.f, 0.f}, sA2[4] = {0.f, 0.f, 0.f, 0.f};

    for (int n = lo + wgid; n < hi; n += AGG_W) {
        int dg = deg[n * DSTR];
        int cnt = dg < CAP ? dg : CAP;
        const unsigned int* bkt = packed + n * CAP;
        float a0 = 0.f, a1 = 0.f, a2 = 0.f, a3 = 0.f, wsum = 0.f;
        for (int e = 0; e < cnt; e += 8) {
            int rem = cnt - e;                     // uniform; >=1
            unsigned int p[8];
#pragma unroll
            for (int j = 0; j < 8; ++j) p[j] = bkt[e + j];     // scalar dwordx8
            ushort4 v[8];
#pragma unroll
            for (int j = 0; j < 8; ++j) {
                int sidx = (j < rem) ? (int)(p[j] & 0xFFFFu) : 0;
                v[j] = xl[(size_t)sidx * 64];
            }
#pragma unroll
            for (int j = 0; j < 8; ++j) {
                float w = (j < rem) ? h2f((unsigned short)(p[j] >> 16)) : 0.f;
                wsum += w;
                a0 = fmaf(w, b2f(v[j].x), a0);
                a1 = fmaf(w, b2f(v[j].y), a1);
                a2 = fmaf(w, b2f(v[j].z), a2);
                a3 = fmaf(w, b2f(v[j].w), a3);
            }
        }
        if (dg > CAP) {                            // exact backstop, ~never taken
            for (int o = 0; o < nov; ++o) {
                int4 E = ovf[o];
                if (E.x == n) {
                    float w = __int_as_float(E.z);
                    ushort4 v = xl[(size_t)E.y * 64];
                    wsum += w;
                    a0 = fmaf(w, b2f(v.x), a0); a1 = fmaf(w, b2f(v.y), a1);
                    a2 = fmaf(w, b2f(v.z), a2); a3 = fmaf(w, b2f(v.w), a3);
                }
            }
        }
        float rz = (wsum == 0.f) ? 1.f : (1.f / wsum);
        ushort4 o;
        o.x = f2b(a0 * rz); o.y = f2b(a1 * rz);
        o.z = f2b(a2 * rz); o.w = f2b(a3 * rz);
        *((ushort4*)avgb + (size_t)n * 64 + l) = o;   // 512B contiguous per node
        float f0 = b2f(o.x), f1 = b2f(o.y), f2v = b2f(o.z), f3 = b2f(o.w);
        sA[0] += f0; sA2[0] += f0 * f0;
        sA[1] += f1; sA2[1] += f1 * f1;
        sA[2] += f2v; sA2[2] += f2v * f2v;
        sA[3] += f3; sA2[3] += f3 * f3;
    }

    __shared__ float ls[256 * 4], ls2[256 * 4];
#pragma unroll
    for (int j = 0; j < 4; ++j) { ls[tid * 4 + j] = sA[j]; ls2[tid * 4 + j] = sA2[j]; }
    __syncthreads();
    if (tid < 64) {
        // channel c = (lane&15)*4 + j; slot tid accumulates channel tid
        int g15 = tid >> 2, j = tid & 3;
        float rs = 0.f, rs2 = 0.f;
#pragma unroll
        for (int k = 0; k < 16; ++k) {
            int st = k * 16 + g15;
            rs += ls[st * 4 + j]; rs2 += ls2[st * 4 + j];
        }
        int slot = (blockIdx.x & (PASLOT - 1)) * 64 + tid;   // 64 adds/address
        atomicAdd(&PA[slot], rs);
        atomicAdd(&PA2[slot], rs2);
    }
}

// stage-2 reduce + BN fold into bf16 W1eff / fp32 b1eff.
// Parallel stage-1: 256 threads = (t-part p, channel cc); max serial loop = 64.
__global__ __launch_bounds__(256) void k_fold(
    const float* __restrict__ W1, const float* __restrict__ b1,
    const float* __restrict__ gamma, const float* __restrict__ beta,
    const float* __restrict__ PX, const float* __restrict__ PX2,
    const float* __restrict__ PA, const float* __restrict__ PA2,
    unsigned short* __restrict__ W1eff, float* __restrict__ b1eff) {
    __shared__ float spx[4][64], spx2[4][64], spa[64], spa2[64];
    __shared__ float gS[192], hS[192];
    int tid = threadIdx.x;
    int p = tid >> 6, cc = tid & 63;
    float s = 0.f, s2 = 0.f;
    for (int b = 0; b < G1; ++b) {          // PX slot = (t*G1 + b)*64 + c, p == t
        int i = (p * G1 + b) * 64 + cc;
        s += PX[i]; s2 += PX2[i];
    }
    spx[p][cc] = s; spx2[p][cc] = s2;
    if (tid < 64) {
        float a = 0.f, a2 = 0.f;
        for (int i = 0; i < PASLOT; ++i) { a += PA[i * 64 + tid]; a2 += PA2[i * 64 + tid]; }
        spa[tid] = a; spa2[tid] = a2;
    }
    __syncthreads();
    const float inv = 1.0f / (float)(TT * NN);
    if (tid < 192) {
        int c = tid;
        float ss, ss2;
        if (c < 64) {
            ss  = spx[0][c] + spx[1][c] + spx[2][c] + spx[3][c];
            ss2 = spx2[0][c] + spx2[1][c] + spx2[2][c] + spx2[3][c];
        } else if (c < 128) {
            int k = c - 64;                 // prev: t=0..2 only
            ss  = spx[0][k] + spx[1][k] + spx[2][k];
            ss2 = spx2[0][k] + spx2[1][k] + spx2[2][k];
        } else {
            int k = c - 128;
            ss = spa[k]; ss2 = spa2[k];
        }
        float mu = ss * inv, ex2 = ss2 * inv;
        float var = ex2 - mu * mu;
        float g = gamma[c] / sqrtf(var + BN_EPS);
        gS[c] = g;
        hS[c] = beta[c] - mu * g;
    }
    __syncthreads();
    if (tid < 192) {
        // slice stride FOLD_B*192 keeps (i mod 192) == tid
        for (int i = blockIdx.x * 192 + tid; i < 64 * 192; i += FOLD_B * 192)
            W1eff[i] = f2b(W1[i] * gS[tid]);
    }
    if (tid < 8) {
        int o = blockIdx.x * 8 + tid;       // 8 blocks x 8 = 64 outputs
        float acc = b1[o];
        for (int c = 0; c < 192; ++c) acc += hS[c] * W1[o * 192 + c];
        b1eff[o] = acc;
    }
}

// MFMA GEMM: block = 4 waves, wave = 16 rows x 64 outs, K=192.
// W1eff register-hoisted (identical for every tile): 24 x short8 = 96 VGPR;
// per tile only 6 A-loads + 24 MFMA + stores. (256,3): 3 blocks/CU resident.
__global__ __launch_bounds__(256, 3) void k_main(
    const unsigned short* __restrict__ xb, const unsigned short* __restrict__ avgb,
    const unsigned short* __restrict__ Wb, const float* __restrict__ bias,
    float* __restrict__ out) {
    int wave = threadIdx.x >> 6;
    int lane = threadIdx.x & 63;
    int m = lane & 15;
    int q = lane >> 4;
    const short8 zf = (short8){0, 0, 0, 0, 0, 0, 0, 0};

    short8 bw[6][4];                        // whole folded W, register-resident
#pragma unroll
    for (int kc = 0; kc < 6; ++kc)
#pragma unroll
        for (int ct = 0; ct < 4; ++ct)
            bw[kc][ct] = *(const short8*)(Wb + (size_t)(ct * 16 + m) * 192 + kc * 32 + q * 8);
    float bv[4];
#pragma unroll
    for (int ct = 0; ct < 4; ++ct) bv[ct] = bias[ct * 16 + m];

    for (int tile = blockIdx.x; tile < (TT * NN) / 64; tile += MAIN_B) {
        int r0 = tile * 64 + wave * 16;     // wave-uniform t (16 divides 50000)
        int t = r0 / NN;
        int n0 = r0 - t * NN;
        size_t nb = (size_t)(n0 + m) * 256 + (size_t)t * 64 + q * 8;
        const unsigned short* xrow = xb + nb;
        const unsigned short* arow = avgb + nb;
        bool has_prev = (t >= 1);

        short8 a[6];                        // all 6 A-frags issued up front
        a[0] = *(const short8*)(xrow);
        a[1] = *(const short8*)(xrow + 32);
        a[2] = has_prev ? *(const short8*)(xrow - 64) : zf;
        a[3] = has_prev ? *(const short8*)(xrow - 32) : zf;
        a[4] = *(const short8*)(arow);
        a[5] = *(const short8*)(arow + 32);

        floatx4 acc[4];
#pragma unroll
        for (int ct = 0; ct < 4; ++ct) acc[ct] = (floatx4){0.f, 0.f, 0.f, 0.f};
#pragma unroll
        for (int kc = 0; kc < 6; ++kc)
#pragma unroll
            for (int ct = 0; ct < 4; ++ct)
                acc[ct] = __builtin_amdgcn_mfma_f32_16x16x32_bf16(a[kc], bw[kc][ct], acc[ct], 0, 0, 0);

#pragma unroll
        for (int ct = 0; ct < 4; ++ct)
#pragma unroll
            for (int i = 0; i < 4; ++i) {
                int row = q * 4 + i;
                __builtin_nontemporal_store(fmaxf(acc[ct][i] + bv[ct], 0.f),
                                            &out[(size_t)(r0 + row) * 64 + ct * 16 + m]);
            }
    }
}

extern "C" void kernel_launch(void* const* d_in, const int* in_sizes, int n_in,
                              void* d_out, int out_size, void* d_ws, size_t ws_size,
                              hipStream_t stream) {
    const float* x     = (const float*)d_in[0];
    const float* ew    = (const float*)d_in[1];
    const float* W1    = (const float*)d_in[2];
    const float* b1    = (const float*)d_in[3];
    const float* gamma = (const float*)d_in[4];
    const float* beta  = (const float*)d_in[5];
    const int*   src   = (const int*)d_in[6];
    const int*   dst   = (const int*)d_in[7];
    float* out = (float*)d_out;
    char*  ws  = (char*)d_ws;

    float* PA       = (float*)(ws + WS_PA);
    float* PA2      = (float*)(ws + WS_PA2);
    float* PX       = (float*)(ws + WS_PX);
    float* PX2      = (float*)(ws + WS_PX2);
    unsigned short* W1eff = (unsigned short*)(ws + WS_W1EFF);
    float* b1eff    = (float*)(ws + WS_B1EFF);
    int*   ovc      = (int*)(ws + WS_OVC);
    int4*  ovf      = (int4*)(ws + WS_OVF);
    int*   deg      = (int*)(ws + WS_DEG);
    unsigned int* packed = (unsigned int*)(ws + WS_PACKED);
    unsigned short* xb   = (unsigned short*)(ws + WS_XB);
    unsigned short* avgb = (unsigned short*)(ws + WS_AVGB);

    k_prep_stats<<<dim3(G1, TT), 256, 0, stream>>>(x, xb, PX, PX2, deg, ovc);

    k_fillB<<<EB, 256, 0, stream>>>(src, dst, ew, deg, packed, ovc, ovf, PA, 0, EHALF);
    k_fillB<<<EB, 256, 0, stream>>>(src, dst, ew, deg, packed, ovc, ovf, PA, EHALF, EE);

    k_agg<<<AGG_B, 256, 0, stream>>>(xb, packed, deg, ovc, ovf, avgb, PA, PA2, 0, NHALF);
    k_agg<<<AGG_B, 256, 0, stream>>>(xb, packed, deg, ovc, ovf, avgb, PA, PA2, NHALF, NN);

    k_fold<<<FOLD_B, 256, 0, stream>>>(W1, b1, gamma, beta, PX, PX2, PA, PA2, W1eff, b1eff);

    k_main<<<MAIN_B, 256, 0, stream>>>(xb, avgb, W1eff, b1eff, out);
}